// Round 1
// baseline (1802.261 us; speedup 1.0000x reference)
//
#include <hip/hip_runtime.h>

typedef __attribute__((ext_vector_type(4))) float f32x4;
typedef __attribute__((ext_vector_type(8))) short short8;
typedef __attribute__((ext_vector_type(4))) unsigned short ushort4v;

__device__ __forceinline__ unsigned short rne_bf16(float f) {
  unsigned int u = __builtin_bit_cast(unsigned int, f);
  u += 0x7FFFu + ((u >> 16) & 1u);
  return (unsigned short)(u >> 16);
}

__device__ __forceinline__ void async16(void* lds, const void* g) {
  __builtin_amdgcn_global_load_lds(
      (const __attribute__((address_space(1))) void*)g,
      (__attribute__((address_space(3))) void*)lds, 16, 0, 0);
}

// ---------------- f32 -> bf16 cast (vectorized, grid-stride) ----------------
__global__ __launch_bounds__(256) void cast_k(const float* __restrict__ in,
                                              unsigned short* __restrict__ out,
                                              int n4) {
  int stride = gridDim.x * 256;
  for (int i = blockIdx.x * 256 + threadIdx.x; i < n4; i += stride) {
    float4 v = ((const float4*)in)[i];
    ushort4v o = {rne_bf16(v.x), rne_bf16(v.y), rne_bf16(v.z), rne_bf16(v.w)};
    ((ushort4v*)out)[i] = o;
  }
}

// ---------------- GEMM: C = A @ B^T, A[M,K] bf16 rm, B[N,K] bf16 rm ----------
// 128x128 tile, BK=32, 4 waves (2x2), 16x16x32 MFMA, global_load_lds staging.
// MODE 0: QKV proj -> write bf16 transposed per head: dst[(b*16+h)][i][tok], *scale
// MODE 1: S = q^T k (batched by z) -> f32 at outF + z*65536, ldc=256
// MODE 2: PV (batched by z)        -> bf16 out_x[( (z>>4)*256 + m )*4096 + (z&15)*256 + n]
// MODE 3: proj -> f32 outF[m*4096+n] + bias[n]
template <int MODE>
__global__ __launch_bounds__(256) void gemm_bt(const unsigned short* __restrict__ Ab,
                                               const unsigned short* __restrict__ Bb,
                                               float* __restrict__ outF,
                                               unsigned short* __restrict__ outB,
                                               const float* __restrict__ bias,
                                               int K, int lda, int ldb, float scale) {
  __shared__ short Ash[128 * 32];
  __shared__ short Bsh[128 * 32];

  const int tid = threadIdx.x;
  const int lane = tid & 63;
  const int wid = tid >> 6;
  const int z = blockIdx.z;
  const int m0 = blockIdx.y * 128;
  const int n0 = blockIdx.x * 128;

  const unsigned short* A = Ab;
  const unsigned short* B = Bb;
  if (MODE == 1 || MODE == 2) {
    A += (size_t)z * 65536;
    B += (size_t)z * 65536;
  }

  const int wm = (wid >> 1) * 64;
  const int wn = (wid & 1) * 64;
  const int fcol = lane & 15;
  const int kslot = (lane >> 4) * 8;

  f32x4 acc[4][4];
#pragma unroll
  for (int r = 0; r < 4; ++r)
#pragma unroll
    for (int s = 0; s < 4; ++s) acc[r][s] = (f32x4){0.f, 0.f, 0.f, 0.f};

  // staging addresses: thread t loads 16B: row = t>>2 (+64), col = (t&3)*8 elems
  const int arow = tid >> 2;
  const int acol = (tid & 3) * 8;
  const unsigned short* gA = A + (size_t)(m0 + arow) * lda + acol;
  const unsigned short* gB = B + (size_t)(n0 + arow) * ldb + acol;
  short* lA = &Ash[tid * 8];
  short* lB = &Bsh[tid * 8];

  for (int kt = 0; kt < K; kt += 32) {
    __syncthreads();  // previous compute done reading LDS
    async16(lA, gA + kt);
    async16(lA + 2048, gA + (size_t)64 * lda + kt);
    async16(lB, gB + kt);
    async16(lB + 2048, gB + (size_t)64 * ldb + kt);
    __syncthreads();  // compiler drains vmcnt before barrier

    short8 a[4], b[4];
#pragma unroll
    for (int r = 0; r < 4; ++r)
      a[r] = *(const short8*)&Ash[(wm + r * 16 + fcol) * 32 + kslot];
#pragma unroll
    for (int s = 0; s < 4; ++s)
      b[s] = *(const short8*)&Bsh[(wn + s * 16 + fcol) * 32 + kslot];
#pragma unroll
    for (int r = 0; r < 4; ++r)
#pragma unroll
      for (int s = 0; s < 4; ++s)
        acc[r][s] = __builtin_amdgcn_mfma_f32_16x16x32_bf16(a[r], b[s], acc[r][s], 0, 0, 0);
  }

  // epilogue: C fragment: col = lane&15, row = (lane>>4)*4 + j
  const int frow = (lane >> 4) * 4;
#pragma unroll
  for (int r = 0; r < 4; ++r) {
#pragma unroll
    for (int s = 0; s < 4; ++s) {
      f32x4 v = acc[r][s];
      const int m = m0 + wm + r * 16 + frow;
      const int n = n0 + wn + s * 16 + fcol;
      if (MODE == 0) {
        // q[b,tok,h,i] -> Qt[(b*16+h)*65536 + i*256 + tok]; j walks tok (contig)
        ushort4v p;
#pragma unroll
        for (int j = 0; j < 4; ++j) p[j] = rne_bf16(v[j] * scale);
        size_t d = ((size_t)((m >> 8) * 16 + (n >> 8))) * 65536 +
                   (size_t)(n & 255) * 256 + (m & 255);
        *(ushort4v*)&outB[d] = p;
      } else if (MODE == 1) {
        float* C = outF + (size_t)z * 65536;
#pragma unroll
        for (int j = 0; j < 4; ++j) C[(size_t)(m + j) * 256 + n] = v[j];
      } else if (MODE == 2) {
        size_t base = ((size_t)((z >> 4) * 256 + m)) * 4096 + (z & 15) * 256 + n;
#pragma unroll
        for (int j = 0; j < 4; ++j) outB[base + (size_t)j * 4096] = rne_bf16(v[j]);
      } else {
        float bv = bias[n];
#pragma unroll
        for (int j = 0; j < 4; ++j) outF[(size_t)(m + j) * 4096 + n] = v[j] + bv;
      }
    }
  }
}

// ---------------- row softmax over 256, in-place f32 + bf16 copy -------------
__global__ __launch_bounds__(256) void softmax_k(float* __restrict__ S,
                                                 unsigned short* __restrict__ P) {
  const int lane = threadIdx.x & 63;
  const size_t row = (size_t)blockIdx.x * 4 + (threadIdx.x >> 6);
  float4 x = *(const float4*)&S[row * 256 + lane * 4];
  float mx = fmaxf(fmaxf(x.x, x.y), fmaxf(x.z, x.w));
#pragma unroll
  for (int off = 32; off; off >>= 1) mx = fmaxf(mx, __shfl_xor(mx, off, 64));
  float e0 = __expf(x.x - mx), e1 = __expf(x.y - mx);
  float e2 = __expf(x.z - mx), e3 = __expf(x.w - mx);
  float s = e0 + e1 + e2 + e3;
#pragma unroll
  for (int off = 32; off; off >>= 1) s += __shfl_xor(s, off, 64);
  const float inv = 1.0f / s;
  e0 *= inv; e1 *= inv; e2 *= inv; e3 *= inv;
  *(float4*)&S[row * 256 + lane * 4] = make_float4(e0, e1, e2, e3);
  ushort4v ob = {rne_bf16(e0), rne_bf16(e1), rne_bf16(e2), rne_bf16(e3)};
  *(ushort4v*)&P[row * 256 + lane * 4] = ob;
}

// -----------------------------------------------------------------------------
extern "C" void kernel_launch(void* const* d_in, const int* in_sizes, int n_in,
                              void* d_out, int out_size, void* d_ws, size_t ws_size,
                              hipStream_t stream) {
  const float* x1 = (const float*)d_in[0];
  const float* x2 = (const float*)d_in[1];
  const float* Wq = (const float*)d_in[2];
  const float* Wk = (const float*)d_in[3];
  const float* Wv = (const float*)d_in[4];
  const float* Wp = (const float*)d_in[5];
  const float* bp = (const float*)d_in[6];

  float* outX = (float*)d_out;                   // x: [8192,4096] f32
  float* outA = outX + (size_t)33554432;         // attn: [512,256,256] f32

  // workspace layout (bf16 elements). Peak use: 369,098,752 bytes.
  unsigned short* Qt  = (unsigned short*)d_ws;   // [512][256][256] (head-transposed)
  unsigned short* Kt  = Qt + 33554432;
  unsigned short* Vt  = Kt + 33554432;
  unsigned short* x1b = Vt + 33554432;           // x1 bf16; later attn bf16
  unsigned short* x2b = x1b + 33554432;          // x2 bf16; later out_x bf16
  unsigned short* Wb  = x2b + 33554432;          // current weight bf16 [4096,4096]

  const float SCALE = 0.0625f;  // 256^-0.5

  cast_k<<<2048, 256, 0, stream>>>(x1, x1b, 8388608);
  cast_k<<<2048, 256, 0, stream>>>(x2, x2b, 8388608);

  // Q = (x1 @ Wq^T) * SCALE  -> Qt[b,h,i,tok]
  cast_k<<<2048, 256, 0, stream>>>(Wq, Wb, 4194304);
  gemm_bt<0><<<dim3(32, 64, 1), 256, 0, stream>>>(x1b, Wb, nullptr, Qt, nullptr,
                                                  4096, 4096, 4096, SCALE);
  // K = x2 @ Wk^T -> Kt
  cast_k<<<2048, 256, 0, stream>>>(Wk, Wb, 4194304);
  gemm_bt<0><<<dim3(32, 64, 1), 256, 0, stream>>>(x2b, Wb, nullptr, Kt, nullptr,
                                                  4096, 4096, 4096, 1.0f);
  // V = x2 @ Wv^T -> Vt
  cast_k<<<2048, 256, 0, stream>>>(Wv, Wb, nullptr ? 0 : 4194304);
  gemm_bt<0><<<dim3(32, 64, 1), 256, 0, stream>>>(x2b, Wb, nullptr, Vt, nullptr,
                                                  4096, 4096, 4096, 1.0f);

  // S = q^T k per head -> f32 logits directly into d_out attn region
  gemm_bt<1><<<dim3(2, 2, 512), 256, 0, stream>>>(Qt, Kt, outA, nullptr, nullptr,
                                                  256, 256, 256, 1.0f);
  // softmax rows in-place; bf16 attn copy into x1b
  softmax_k<<<32768, 256, 0, stream>>>(outA, x1b);
  // out = attn @ v per head -> bf16 x-layout into x2b
  gemm_bt<2><<<dim3(2, 2, 512), 256, 0, stream>>>(x1b, Vt, nullptr, x2b, nullptr,
                                                  256, 256, 256, 1.0f);

  // x = out @ Wp^T + bp -> d_out
  cast_k<<<2048, 256, 0, stream>>>(Wp, Wb, 4194304);
  gemm_bt<3><<<dim3(32, 64, 1), 256, 0, stream>>>(x2b, Wb, outX, nullptr, bp,
                                                  4096, 4096, 4096, 1.0f);
}

// Round 2
// 1341.640 us; speedup vs baseline: 1.3433x; 1.3433x over previous
//
#include <hip/hip_runtime.h>

typedef __attribute__((ext_vector_type(4))) float f32x4;
typedef __attribute__((ext_vector_type(8))) short short8;
typedef __attribute__((ext_vector_type(4))) unsigned short ushort4v;

__device__ __forceinline__ unsigned short rne_bf16(float f) {
  unsigned int u = __builtin_bit_cast(unsigned int, f);
  u += 0x7FFFu + ((u >> 16) & 1u);
  return (unsigned short)(u >> 16);
}

__device__ __forceinline__ void async16(void* lds, const void* g) {
  __builtin_amdgcn_global_load_lds(
      (const __attribute__((address_space(1))) void*)g,
      (__attribute__((address_space(3))) void*)lds, 16, 0, 0);
}

__device__ __forceinline__ f32x4 mfma16(short8 a, short8 b, f32x4 c) {
  return __builtin_amdgcn_mfma_f32_16x16x32_bf16(a, b, c, 0, 0, 0);
}

// ---------------- f32 -> bf16 cast (vectorized, grid-stride) ----------------
__global__ __launch_bounds__(256) void cast_k(const float* __restrict__ in,
                                              unsigned short* __restrict__ out,
                                              int n4) {
  int stride = gridDim.x * 256;
  for (int i = blockIdx.x * 256 + threadIdx.x; i < n4; i += stride) {
    float4 v = ((const float4*)in)[i];
    ushort4v o = {rne_bf16(v.x), rne_bf16(v.y), rne_bf16(v.z), rne_bf16(v.w)};
    ((ushort4v*)out)[i] = o;
  }
}

// ============ 256x256-tile 8-phase GEMM: C = A @ B^T (bf16 in, K%64==0) ======
// 8 waves (2M x 4N), BK=64 in two K-halves, 128 KiB LDS double-buffered.
// LDS per buffer: A[2 kh][256 row][32 col] + B[...]; chunk-XOR swizzle
// (chunk ^= (row>>1)&3) applied on pre-swizzled global src AND on ds_read.
// Counted vmcnt(6) once per K-tile; setprio around each 16-MFMA cluster.
// MODE 0: QKV proj -> bf16 head-transposed dst[(b*16+h)][i][tok], *scale
// MODE 3: out proj -> f32 outF[m*4096+n] + bias[n]
template <int MODE>
__global__ __launch_bounds__(512, 2) void gemm256(const unsigned short* __restrict__ A,
                                                  const unsigned short* __restrict__ B,
                                                  float* __restrict__ outF,
                                                  unsigned short* __restrict__ outB,
                                                  const float* __restrict__ bias,
                                                  int K, int lda, int ldb,
                                                  float scale, int gx) {
  __shared__ unsigned short lds[65536];  // 128 KiB
  const int tid = threadIdx.x;
  const int lane = tid & 63;
  const int wid = tid >> 6;
  const int wm = wid >> 2;  // 0..1 -> 128 rows each
  const int wn = wid & 3;   // 0..3 -> 64 cols each
  int lin = blockIdx.x;
  lin = (lin & 7) * (gridDim.x >> 3) + (lin >> 3);  // XCD swizzle (grid%8==0)
  const int bx = lin % gx;
  const int by = lin / gx;
  const int m0 = by * 256, n0 = bx * 256;
  const int NT = K >> 6;

  // ---- staging addresses (2 x global_load_lds x16B per half-tile per thread)
  // thread t covers LDS linear slot p = tid (+512), row=p>>2, chunk=p&3.
  const int gsw8 = (((tid & 3) ^ ((tid >> 3) & 3))) * 8;  // pre-swizzled col
  const unsigned short* gA = A + (size_t)(m0 + (tid >> 2)) * lda + gsw8;
  const unsigned short* gB = B + (size_t)(n0 + (tid >> 2)) * ldb + gsw8;
  const size_t astep = (size_t)128 * lda;
  const size_t bstep = (size_t)128 * ldb;
  unsigned short* ld0 = &lds[tid * 8];

#define STG_A(kt, kh, bf) do { \
    const unsigned short* s_ = gA + (kt) + (kh) * 32; \
    unsigned short* d_ = ld0 + (bf) * 32768 + (kh) * 8192; \
    async16(d_, s_); async16(d_ + 4096, s_ + astep); } while (0)
#define STG_B(kt, kh, bf) do { \
    const unsigned short* s_ = gB + (kt) + (kh) * 32; \
    unsigned short* d_ = ld0 + 16384 + (bf) * 32768 + (kh) * 8192; \
    async16(d_, s_); async16(d_ + 4096, s_ + bstep); } while (0)

  // ---- ds_read addresses (swizzled chunk; conflict-free: 8 distinct quads)
  const int rl = lane & 15;
  const int ch = (lane >> 4) ^ ((rl >> 1) & 3);
  const int aidx = wm * 4096 + rl * 32 + ch * 8;           // + bb + kh*8192 + r*512
  const int bidx = 16384 + wn * 2048 + rl * 32 + ch * 8;   // + bb + kh*8192 + s*512

  f32x4 acc[8][4];
#pragma unroll
  for (int r = 0; r < 8; ++r)
#pragma unroll
    for (int s = 0; s < 4; ++s) acc[r][s] = (f32x4){0.f, 0.f, 0.f, 0.f};

  // ---- prologue: tile0 all 4 halves; tile1 first 3 halves; wait tile0
  STG_A(0, 0, 0); STG_B(0, 0, 0); STG_A(0, 1, 0); STG_B(0, 1, 0);
  if (NT > 1) {
    STG_A(64, 0, 1); STG_B(64, 0, 1); STG_A(64, 1, 1);
    asm volatile("s_waitcnt vmcnt(6)" ::: "memory");
  } else {
    asm volatile("s_waitcnt vmcnt(0)" ::: "memory");
  }
  __builtin_amdgcn_s_barrier();

  short8 af[8];
  for (int t = 0; t < NT; ++t) {
    const int bb = (t & 1) * 32768;
    // ---- P1 (kh=0): read A rows 0-7 + B cols 0-1; stage (t+1).B-k1
    {
      short8 b0 = *(const short8*)&lds[bb + bidx];
      short8 b1 = *(const short8*)&lds[bb + bidx + 512];
#pragma unroll
      for (int r = 0; r < 8; ++r) af[r] = *(const short8*)&lds[bb + aidx + r * 512];
      if (t + 1 < NT) STG_B((t + 1) * 64, 1, (t + 1) & 1);
      __builtin_amdgcn_s_barrier();
      asm volatile("s_waitcnt lgkmcnt(0)" ::: "memory");
      __builtin_amdgcn_s_setprio(1);
#pragma unroll
      for (int r = 0; r < 8; ++r) {
        acc[r][0] = mfma16(af[r], b0, acc[r][0]);
        acc[r][1] = mfma16(af[r], b1, acc[r][1]);
      }
      __builtin_amdgcn_s_setprio(0);
      __builtin_amdgcn_s_barrier();
    }
    // ---- P2 (kh=0): read B cols 2-3; stage (t+2).A-k0
    {
      short8 b2 = *(const short8*)&lds[bb + bidx + 1024];
      short8 b3 = *(const short8*)&lds[bb + bidx + 1536];
      if (t + 2 < NT) STG_A((t + 2) * 64, 0, t & 1);
      __builtin_amdgcn_s_barrier();
      asm volatile("s_waitcnt lgkmcnt(0)" ::: "memory");
      __builtin_amdgcn_s_setprio(1);
#pragma unroll
      for (int r = 0; r < 8; ++r) {
        acc[r][2] = mfma16(af[r], b2, acc[r][2]);
        acc[r][3] = mfma16(af[r], b3, acc[r][3]);
      }
      __builtin_amdgcn_s_setprio(0);
      __builtin_amdgcn_s_barrier();
    }
    // ---- P3 (kh=1): read A rows 0-7 + B cols 0-1; stage (t+2).B-k0
    {
      short8 b0 = *(const short8*)&lds[bb + 8192 + bidx];
      short8 b1 = *(const short8*)&lds[bb + 8192 + bidx + 512];
#pragma unroll
      for (int r = 0; r < 8; ++r) af[r] = *(const short8*)&lds[bb + 8192 + aidx + r * 512];
      if (t + 2 < NT) STG_B((t + 2) * 64, 0, t & 1);
      __builtin_amdgcn_s_barrier();
      asm volatile("s_waitcnt lgkmcnt(0)" ::: "memory");
      __builtin_amdgcn_s_setprio(1);
#pragma unroll
      for (int r = 0; r < 8; ++r) {
        acc[r][0] = mfma16(af[r], b0, acc[r][0]);
        acc[r][1] = mfma16(af[r], b1, acc[r][1]);
      }
      __builtin_amdgcn_s_setprio(0);
      __builtin_amdgcn_s_barrier();
    }
    // ---- P4 (kh=1): read B cols 2-3; stage (t+2).A-k1; tile-boundary vmcnt
    {
      short8 b2 = *(const short8*)&lds[bb + 8192 + bidx + 1024];
      short8 b3 = *(const short8*)&lds[bb + 8192 + bidx + 1536];
      if (t + 2 < NT) STG_A((t + 2) * 64, 1, t & 1);
      __builtin_amdgcn_s_barrier();
      asm volatile("s_waitcnt lgkmcnt(0)" ::: "memory");
      __builtin_amdgcn_s_setprio(1);
#pragma unroll
      for (int r = 0; r < 8; ++r) {
        acc[r][2] = mfma16(af[r], b2, acc[r][2]);
        acc[r][3] = mfma16(af[r], b3, acc[r][3]);
      }
      __builtin_amdgcn_s_setprio(0);
      if (t + 1 < NT) {
        if (t + 1 == NT - 1) asm volatile("s_waitcnt vmcnt(0)" ::: "memory");
        else                 asm volatile("s_waitcnt vmcnt(6)" ::: "memory");
      }
      __builtin_amdgcn_s_barrier();
    }
  }
#undef STG_A
#undef STG_B

  // ---- epilogue: C frag col = lane&15, row = (lane>>4)*4 + j
  const int fcol = lane & 15;
  const int frow = (lane >> 4) * 4;
#pragma unroll
  for (int r = 0; r < 8; ++r) {
#pragma unroll
    for (int s = 0; s < 4; ++s) {
      f32x4 v = acc[r][s];
      const int m = m0 + wm * 128 + r * 16 + frow;
      const int n = n0 + wn * 64 + s * 16 + fcol;
      if (MODE == 0) {
        ushort4v p;
#pragma unroll
        for (int j = 0; j < 4; ++j) p[j] = rne_bf16(v[j] * scale);
        size_t d = ((size_t)((m >> 8) * 16 + (n >> 8))) * 65536 +
                   (size_t)(n & 255) * 256 + (m & 255);
        *(ushort4v*)&outB[d] = p;
      } else {
        float bv = bias[n];
#pragma unroll
        for (int j = 0; j < 4; ++j) outF[(size_t)(m + j) * 4096 + n] = v[j] + bv;
      }
    }
  }
}

// ---------------- 128x128 GEMM (old structure) for the small batched mats ----
// MODE 1: S = q^T k (batched by z) -> f32 at outF + z*65536, ldc=256
// MODE 2: PV (batched by z)        -> bf16 out_x[((z>>4)*256+m)*4096+(z&15)*256+n]
template <int MODE>
__global__ __launch_bounds__(256) void gemm_bt(const unsigned short* __restrict__ Ab,
                                               const unsigned short* __restrict__ Bb,
                                               float* __restrict__ outF,
                                               unsigned short* __restrict__ outB,
                                               int K, int lda, int ldb) {
  __shared__ short Ash[128 * 32];
  __shared__ short Bsh[128 * 32];

  const int tid = threadIdx.x;
  const int lane = tid & 63;
  const int wid = tid >> 6;
  const int z = blockIdx.z;
  const int m0 = blockIdx.y * 128;
  const int n0 = blockIdx.x * 128;

  const unsigned short* A = Ab + (size_t)z * 65536;
  const unsigned short* B = Bb + (size_t)z * 65536;

  const int wm = (wid >> 1) * 64;
  const int wn = (wid & 1) * 64;
  const int fcol = lane & 15;
  const int kslot = (lane >> 4) * 8;

  f32x4 acc[4][4];
#pragma unroll
  for (int r = 0; r < 4; ++r)
#pragma unroll
    for (int s = 0; s < 4; ++s) acc[r][s] = (f32x4){0.f, 0.f, 0.f, 0.f};

  const int arow = tid >> 2;
  const int acol = (tid & 3) * 8;
  const unsigned short* gA = A + (size_t)(m0 + arow) * lda + acol;
  const unsigned short* gB = B + (size_t)(n0 + arow) * ldb + acol;
  short* lA = &Ash[tid * 8];
  short* lB = &Bsh[tid * 8];

  for (int kt = 0; kt < K; kt += 32) {
    __syncthreads();
    async16(lA, gA + kt);
    async16(lA + 2048, gA + (size_t)64 * lda + kt);
    async16(lB, gB + kt);
    async16(lB + 2048, gB + (size_t)64 * ldb + kt);
    __syncthreads();

    short8 a[4], b[4];
#pragma unroll
    for (int r = 0; r < 4; ++r)
      a[r] = *(const short8*)&Ash[(wm + r * 16 + fcol) * 32 + kslot];
#pragma unroll
    for (int s = 0; s < 4; ++s)
      b[s] = *(const short8*)&Bsh[(wn + s * 16 + fcol) * 32 + kslot];
#pragma unroll
    for (int r = 0; r < 4; ++r)
#pragma unroll
      for (int s = 0; s < 4; ++s)
        acc[r][s] = __builtin_amdgcn_mfma_f32_16x16x32_bf16(a[r], b[s], acc[r][s], 0, 0, 0);
  }

  const int frow = (lane >> 4) * 4;
#pragma unroll
  for (int r = 0; r < 4; ++r) {
#pragma unroll
    for (int s = 0; s < 4; ++s) {
      f32x4 v = acc[r][s];
      const int m = m0 + wm + r * 16 + frow;
      const int n = n0 + wn + s * 16 + fcol;
      if (MODE == 1) {
        float* C = outF + (size_t)z * 65536;
#pragma unroll
        for (int j = 0; j < 4; ++j) C[(size_t)(m + j) * 256 + n] = v[j];
      } else {
        size_t base = ((size_t)((z >> 4) * 256 + m)) * 4096 + (z & 15) * 256 + n;
#pragma unroll
        for (int j = 0; j < 4; ++j) outB[base + (size_t)j * 4096] = rne_bf16(v[j]);
      }
    }
  }
}

// ---------------- row softmax over 256, in-place f32 + bf16 copy -------------
__global__ __launch_bounds__(256) void softmax_k(float* __restrict__ S,
                                                 unsigned short* __restrict__ P) {
  const int lane = threadIdx.x & 63;
  const size_t row = (size_t)blockIdx.x * 4 + (threadIdx.x >> 6);
  float4 x = *(const float4*)&S[row * 256 + lane * 4];
  float mx = fmaxf(fmaxf(x.x, x.y), fmaxf(x.z, x.w));
#pragma unroll
  for (int off = 32; off; off >>= 1) mx = fmaxf(mx, __shfl_xor(mx, off, 64));
  float e0 = __expf(x.x - mx), e1 = __expf(x.y - mx);
  float e2 = __expf(x.z - mx), e3 = __expf(x.w - mx);
  float s = e0 + e1 + e2 + e3;
#pragma unroll
  for (int off = 32; off; off >>= 1) s += __shfl_xor(s, off, 64);
  const float inv = 1.0f / s;
  e0 *= inv; e1 *= inv; e2 *= inv; e3 *= inv;
  *(float4*)&S[row * 256 + lane * 4] = make_float4(e0, e1, e2, e3);
  ushort4v ob = {rne_bf16(e0), rne_bf16(e1), rne_bf16(e2), rne_bf16(e3)};
  *(ushort4v*)&P[row * 256 + lane * 4] = ob;
}

// -----------------------------------------------------------------------------
extern "C" void kernel_launch(void* const* d_in, const int* in_sizes, int n_in,
                              void* d_out, int out_size, void* d_ws, size_t ws_size,
                              hipStream_t stream) {
  const float* x1 = (const float*)d_in[0];
  const float* x2 = (const float*)d_in[1];
  const float* Wq = (const float*)d_in[2];
  const float* Wk = (const float*)d_in[3];
  const float* Wv = (const float*)d_in[4];
  const float* Wp = (const float*)d_in[5];
  const float* bp = (const float*)d_in[6];

  float* outX = (float*)d_out;                   // x: [8192,4096] f32
  float* outA = outX + (size_t)33554432;         // attn: [512,256,256] f32

  unsigned short* Qt  = (unsigned short*)d_ws;   // [512][256][256] head-transposed
  unsigned short* Kt  = Qt + 33554432;
  unsigned short* Vt  = Kt + 33554432;
  unsigned short* x1b = Vt + 33554432;           // x1 bf16; later attn bf16
  unsigned short* x2b = x1b + 33554432;          // x2 bf16; later out_x bf16
  unsigned short* Wb  = x2b + 33554432;          // current weight bf16 [4096,4096]

  const float SCALE = 0.0625f;  // 256^-0.5

  cast_k<<<2048, 256, 0, stream>>>(x1, x1b, 8388608);
  cast_k<<<2048, 256, 0, stream>>>(x2, x2b, 8388608);

  // Q = (x1 @ Wq^T) * SCALE -> Qt[b,h,i,tok]
  cast_k<<<2048, 256, 0, stream>>>(Wq, Wb, 4194304);
  gemm256<0><<<512, 512, 0, stream>>>(x1b, Wb, nullptr, Qt, nullptr,
                                      4096, 4096, 4096, SCALE, 16);
  // K = x2 @ Wk^T -> Kt
  cast_k<<<2048, 256, 0, stream>>>(Wk, Wb, 4194304);
  gemm256<0><<<512, 512, 0, stream>>>(x2b, Wb, nullptr, Kt, nullptr,
                                      4096, 4096, 4096, 1.0f, 16);
  // V = x2 @ Wv^T -> Vt
  cast_k<<<2048, 256, 0, stream>>>(Wv, Wb, 4194304);
  gemm256<0><<<512, 512, 0, stream>>>(x2b, Wb, nullptr, Vt, nullptr,
                                      4096, 4096, 4096, 1.0f, 16);

  // S = q^T k per head -> f32 logits into d_out attn region
  gemm_bt<1><<<dim3(2, 2, 512), 256, 0, stream>>>(Qt, Kt, outA, nullptr, 256, 256, 256);
  // softmax rows in-place; bf16 attn copy into x1b
  softmax_k<<<32768, 256, 0, stream>>>(outA, x1b);
  // out = attn @ v per head -> bf16 x-layout into x2b
  gemm_bt<2><<<dim3(2, 2, 512), 256, 0, stream>>>(x1b, Vt, nullptr, x2b, 256, 256, 256);

  // x = out @ Wp^T + bp -> d_out
  cast_k<<<2048, 256, 0, stream>>>(Wp, Wb, 4194304);
  gemm256<3><<<512, 512, 0, stream>>>(x2b, Wb, outX, nullptr, bp,
                                      4096, 4096, 4096, 1.0f, 16);
}

// Round 4
// 1322.538 us; speedup vs baseline: 1.3627x; 1.0144x over previous
//
#include <hip/hip_runtime.h>

typedef __attribute__((ext_vector_type(4))) float f32x4;
typedef __attribute__((ext_vector_type(8))) short short8;
typedef __attribute__((ext_vector_type(4))) unsigned short ushort4v;

__device__ __forceinline__ unsigned short rne_bf16(float f) {
  unsigned int u = __builtin_bit_cast(unsigned int, f);
  u += 0x7FFFu + ((u >> 16) & 1u);
  return (unsigned short)(u >> 16);
}

__device__ __forceinline__ void async16(void* lds, const void* g) {
  __builtin_amdgcn_global_load_lds(
      (const __attribute__((address_space(1))) void*)g,
      (__attribute__((address_space(3))) void*)lds, 16, 0, 0);
}

__device__ __forceinline__ f32x4 mfma16(short8 a, short8 b, f32x4 c) {
  return __builtin_amdgcn_mfma_f32_16x16x32_bf16(a, b, c, 0, 0, 0);
}

// ---------------- f32 -> bf16 cast (vectorized, grid-stride) ----------------
__global__ __launch_bounds__(256) void cast_k(const float* __restrict__ in,
                                              unsigned short* __restrict__ out,
                                              int n4) {
  int stride = gridDim.x * 256;
  for (int i = blockIdx.x * 256 + threadIdx.x; i < n4; i += stride) {
    float4 v = ((const float4*)in)[i];
    ushort4v o = {rne_bf16(v.x), rne_bf16(v.y), rne_bf16(v.z), rne_bf16(v.w)};
    ((ushort4v*)out)[i] = o;
  }
}

// ============ 256x256-tile GEMM: C = A @ B^T (bf16 in, K%64==0, K>=128) ======
// 8 waves (2M x 4N), BK=64 as two kh-phases, 128 KiB LDS = 4 regions of 32KB
// (region r: A at r-derived offset, B at +16384 shorts). Phase P (=2t+kh) uses
// region P%4. Per phase: READ_A(this, 8xb128, issued first -> compiler staggers
// lgkm under MFMA), READ_B(next phase, double-buffered bf0/bf1), STG(phase P+3,
// 4 gloads), sched_barrier, 32 MFMA (setprio), then gate vmcnt(4 if this phase
// staged else 0) + s_barrier. Safety: every ds_read happens AFTER a barrier
// that follows every wave's vmcnt-retire of the staging gloads for that region;
// every STG overwrites a region whose readers' MFMAs completed before the
// previous barrier.
// MODE 0: QKV proj -> bf16 head-transposed dst[(b*16+h)][i][tok], *scale
// MODE 3: out proj -> f32 outF[m*4096+n] + bias[n]
template <int MODE>
__global__ __launch_bounds__(512, 2) void gemm256(const unsigned short* __restrict__ A,
                                                  const unsigned short* __restrict__ B,
                                                  float* __restrict__ outF,
                                                  unsigned short* __restrict__ outB,
                                                  const float* __restrict__ bias,
                                                  int K, int lda, int ldb,
                                                  float scale, int gx) {
  __shared__ unsigned short lds[65536];  // 128 KiB
  const int tid = threadIdx.x;
  const int lane = tid & 63;
  const int wid = tid >> 6;
  const int wm = wid >> 2;  // 0..1 -> 128 rows each
  const int wn = wid & 3;   // 0..3 -> 64 cols each
  int lin = blockIdx.x;
  lin = (lin & 7) * (gridDim.x >> 3) + (lin >> 3);  // XCD swizzle (grid%8==0)
  const int bx = lin % gx;
  const int by = lin / gx;
  const int m0 = by * 256, n0 = bx * 256;
  const int NT = K >> 6;

  // staging: thread t covers LDS slot p = tid (+512): row=p>>2, chunk=p&3
  const int gsw8 = (((tid & 3) ^ ((tid >> 3) & 3))) * 8;  // pre-swizzled col
  const unsigned short* gA = A + (size_t)(m0 + (tid >> 2)) * lda + gsw8;
  const unsigned short* gB = B + (size_t)(n0 + (tid >> 2)) * ldb + gsw8;
  const size_t astep = (size_t)128 * lda;
  const size_t bstep = (size_t)128 * ldb;
  unsigned short* ld0 = &lds[tid * 8];

// STG(Q): stage phase Q's region: tile Q>>1 at kh Q&1 into buf (Q>>1)&1
#define STG(Q) do { \
    const int kt_ = ((Q) >> 1) * 64 + ((Q) & 1) * 32; \
    const int off_ = (((Q) >> 1) & 1) * 32768 + ((Q) & 1) * 8192; \
    const unsigned short* sA_ = gA + kt_; \
    unsigned short* dA_ = ld0 + off_; \
    async16(dA_, sA_); async16(dA_ + 4096, sA_ + astep); \
    const unsigned short* sB_ = gB + kt_; \
    unsigned short* dB_ = ld0 + 16384 + off_; \
    async16(dB_, sB_); async16(dB_ + 4096, sB_ + bstep); } while (0)

  // ds_read addresses (swizzled chunk; conflict-free)
  const int rl = lane & 15;
  const int ch = (lane >> 4) ^ ((rl >> 1) & 3);
  const int aidx = wm * 4096 + rl * 32 + ch * 8;           // + region base + r*512
  const int bidx = 16384 + wn * 2048 + rl * 32 + ch * 8;   // + region base + s*512

  short8 af[8], bf0[4], bf1[4];
#define READ_A(base) do { \
    _Pragma("unroll") \
    for (int r_ = 0; r_ < 8; ++r_) af[r_] = *(const short8*)&lds[(base) + aidx + r_ * 512]; \
  } while (0)
#define READ_B(base, dst) do { \
    _Pragma("unroll") \
    for (int s_ = 0; s_ < 4; ++s_) dst[s_] = *(const short8*)&lds[(base) + bidx + s_ * 512]; \
  } while (0)

  f32x4 acc[8][4];
#pragma unroll
  for (int r = 0; r < 8; ++r)
#pragma unroll
    for (int s = 0; s < 4; ++s) acc[r][s] = (f32x4){0.f, 0.f, 0.f, 0.f};

#define MFMA32(bfX) do { \
    __builtin_amdgcn_s_setprio(1); \
    _Pragma("unroll") \
    for (int r_ = 0; r_ < 8; ++r_) \
      _Pragma("unroll") \
      for (int s_ = 0; s_ < 4; ++s_) acc[r_][s_] = mfma16(af[r_], bfX[s_], acc[r_][s_]); \
    __builtin_amdgcn_s_setprio(0); \
  } while (0)

  // ---- prologue: stage phases 0,1,2; retire 0,1; publish; prefetch bf(ph0)
  STG(0); STG(1); STG(2);
  asm volatile("s_waitcnt vmcnt(4)" ::: "memory");
  __builtin_amdgcn_s_barrier();
  READ_B(0, bf0);

  for (int t = 0; t < NT; ++t) {
    const int bb = (t & 1) * 32768;
    // ---- phase A (P=2t, kh0): consume bf0, prefetch bf1
    READ_A(bb);
    READ_B(bb + 8192, bf1);            // ph 2t+1 (same tile, staged with it)
    if (t + 1 < NT) STG(2 * t + 3);    // tile t+1, kh1
    __builtin_amdgcn_sched_barrier(0);
    MFMA32(bf0);
    if (t + 1 < NT) asm volatile("s_waitcnt vmcnt(4)" ::: "memory");
    else            asm volatile("s_waitcnt vmcnt(0)" ::: "memory");
    __builtin_amdgcn_s_barrier();
    // ---- phase B (P=2t+1, kh1): consume bf1, prefetch bf0
    READ_A(bb + 8192);
    if (t + 1 < NT) {
      READ_B(((t + 1) & 1) * 32768, bf0);  // ph 2t+2
      if (t + 2 < NT) STG(2 * t + 4);      // tile t+2, kh0
    }
    __builtin_amdgcn_sched_barrier(0);
    MFMA32(bf1);
    if (t + 1 < NT) {
      if (t + 2 < NT) asm volatile("s_waitcnt vmcnt(4)" ::: "memory");
      else            asm volatile("s_waitcnt vmcnt(0)" ::: "memory");
      __builtin_amdgcn_s_barrier();
    }
  }
#undef STG
#undef READ_A
#undef READ_B
#undef MFMA32

  // ---- epilogue: C frag col = lane&15, row = (lane>>4)*4 + j
  const int fcol = lane & 15;
  const int frow = (lane >> 4) * 4;
#pragma unroll
  for (int r = 0; r < 8; ++r) {
#pragma unroll
    for (int s = 0; s < 4; ++s) {
      f32x4 v = acc[r][s];
      const int m = m0 + wm * 128 + r * 16 + frow;
      const int n = n0 + wn * 64 + s * 16 + fcol;
      if (MODE == 0) {
        ushort4v p;
#pragma unroll
        for (int j = 0; j < 4; ++j) p[j] = rne_bf16(v[j] * scale);
        size_t d = ((size_t)((m >> 8) * 16 + (n >> 8))) * 65536 +
                   (size_t)(n & 255) * 256 + (m & 255);
        *(ushort4v*)&outB[d] = p;
      } else {
        float bv = bias[n];
#pragma unroll
        for (int j = 0; j < 4; ++j) outF[(size_t)(m + j) * 4096 + n] = v[j] + bv;
      }
    }
  }
}

// ---------------- 128x128 GEMM for the small batched mats --------------------
// MODE 1: S = q^T k (batched by z) -> f32 at outF + z*65536, ldc=256
// MODE 2: PV (batched by z)        -> bf16 out_x[((z>>4)*256+m)*4096+(z&15)*256+n]
template <int MODE>
__global__ __launch_bounds__(256) void gemm_bt(const unsigned short* __restrict__ Ab,
                                               const unsigned short* __restrict__ Bb,
                                               float* __restrict__ outF,
                                               unsigned short* __restrict__ outB,
                                               int K, int lda, int ldb) {
  __shared__ short Ash[128 * 32];
  __shared__ short Bsh[128 * 32];

  const int tid = threadIdx.x;
  const int lane = tid & 63;
  const int wid = tid >> 6;
  const int z = blockIdx.z;
  const int m0 = blockIdx.y * 128;
  const int n0 = blockIdx.x * 128;

  const unsigned short* A = Ab + (size_t)z * 65536;
  const unsigned short* B = Bb + (size_t)z * 65536;

  const int wm = (wid >> 1) * 64;
  const int wn = (wid & 1) * 64;
  const int fcol = lane & 15;
  const int kslot = (lane >> 4) * 8;

  f32x4 acc[4][4];
#pragma unroll
  for (int r = 0; r < 4; ++r)
#pragma unroll
    for (int s = 0; s < 4; ++s) acc[r][s] = (f32x4){0.f, 0.f, 0.f, 0.f};

  const int arow = tid >> 2;
  const int acol = (tid & 3) * 8;
  const unsigned short* gA = A + (size_t)(m0 + arow) * lda + acol;
  const unsigned short* gB = B + (size_t)(n0 + arow) * ldb + acol;
  short* lA = &Ash[tid * 8];
  short* lB = &Bsh[tid * 8];

  for (int kt = 0; kt < K; kt += 32) {
    __syncthreads();
    async16(lA, gA + kt);
    async16(lA + 2048, gA + (size_t)64 * lda + kt);
    async16(lB, gB + kt);
    async16(lB + 2048, gB + (size_t)64 * ldb + kt);
    __syncthreads();

    short8 a[4], b[4];
#pragma unroll
    for (int r = 0; r < 4; ++r)
      a[r] = *(const short8*)&Ash[(wm + r * 16 + fcol) * 32 + kslot];
#pragma unroll
    for (int s = 0; s < 4; ++s)
      b[s] = *(const short8*)&Bsh[(wn + s * 16 + fcol) * 32 + kslot];
#pragma unroll
    for (int r = 0; r < 4; ++r)
#pragma unroll
      for (int s = 0; s < 4; ++s)
        acc[r][s] = __builtin_amdgcn_mfma_f32_16x16x32_bf16(a[r], b[s], acc[r][s], 0, 0, 0);
  }

  const int frow = (lane >> 4) * 4;
#pragma unroll
  for (int r = 0; r < 4; ++r) {
#pragma unroll
    for (int s = 0; s < 4; ++s) {
      f32x4 v = acc[r][s];
      const int m = m0 + wm + r * 16 + frow;
      const int n = n0 + wn + s * 16 + fcol;
      if (MODE == 1) {
        float* C = outF + (size_t)z * 65536;
#pragma unroll
        for (int j = 0; j < 4; ++j) C[(size_t)(m + j) * 256 + n] = v[j];
      } else {
        size_t base = ((size_t)((z >> 4) * 256 + m)) * 4096 + (z & 15) * 256 + n;
#pragma unroll
        for (int j = 0; j < 4; ++j) outB[base + (size_t)j * 4096] = rne_bf16(v[j]);
      }
    }
  }
}

// ---------------- row softmax over 256, in-place f32 + bf16 copy -------------
__global__ __launch_bounds__(256) void softmax_k(float* __restrict__ S,
                                                 unsigned short* __restrict__ P) {
  const int lane = threadIdx.x & 63;
  const size_t row = (size_t)blockIdx.x * 4 + (threadIdx.x >> 6);
  float4 x = *(const float4*)&S[row * 256 + lane * 4];
  float mx = fmaxf(fmaxf(x.x, x.y), fmaxf(x.z, x.w));
#pragma unroll
  for (int off = 32; off; off >>= 1) mx = fmaxf(mx, __shfl_xor(mx, off, 64));
  float e0 = __expf(x.x - mx), e1 = __expf(x.y - mx);
  float e2 = __expf(x.z - mx), e3 = __expf(x.w - mx);
  float s = e0 + e1 + e2 + e3;
#pragma unroll
  for (int off = 32; off; off >>= 1) s += __shfl_xor(s, off, 64);
  const float inv = 1.0f / s;
  e0 *= inv; e1 *= inv; e2 *= inv; e3 *= inv;
  *(float4*)&S[row * 256 + lane * 4] = make_float4(e0, e1, e2, e3);
  ushort4v ob = {rne_bf16(e0), rne_bf16(e1), rne_bf16(e2), rne_bf16(e3)};
  *(ushort4v*)&P[row * 256 + lane * 4] = ob;
}

// -----------------------------------------------------------------------------
extern "C" void kernel_launch(void* const* d_in, const int* in_sizes, int n_in,
                              void* d_out, int out_size, void* d_ws, size_t ws_size,
                              hipStream_t stream) {
  const float* x1 = (const float*)d_in[0];
  const float* x2 = (const float*)d_in[1];
  const float* Wq = (const float*)d_in[2];
  const float* Wk = (const float*)d_in[3];
  const float* Wv = (const float*)d_in[4];
  const float* Wp = (const float*)d_in[5];
  const float* bp = (const float*)d_in[6];

  float* outX = (float*)d_out;                   // x: [8192,4096] f32
  float* outA = outX + (size_t)33554432;         // attn: [512,256,256] f32

  unsigned short* Qt  = (unsigned short*)d_ws;   // [512][256][256] head-transposed
  unsigned short* Kt  = Qt + 33554432;
  unsigned short* Vt  = Kt + 33554432;
  unsigned short* x1b = Vt + 33554432;           // x1 bf16; later attn bf16
  unsigned short* x2b = x1b + 33554432;          // x2 bf16; later out_x bf16
  unsigned short* Wb  = x2b + 33554432;          // current weight bf16 [4096,4096]

  const float SCALE = 0.0625f;  // 256^-0.5

  cast_k<<<2048, 256, 0, stream>>>(x1, x1b, 8388608);
  cast_k<<<2048, 256, 0, stream>>>(x2, x2b, 8388608);

  // Q = (x1 @ Wq^T) * SCALE -> Qt[b,h,i,tok]
  cast_k<<<2048, 256, 0, stream>>>(Wq, Wb, 4194304);
  gemm256<0><<<512, 512, 0, stream>>>(x1b, Wb, nullptr, Qt, nullptr,
                                      4096, 4096, 4096, SCALE, 16);
  // K = x2 @ Wk^T -> Kt
  cast_k<<<2048, 256, 0, stream>>>(Wk, Wb, 4194304);
  gemm256<0><<<512, 512, 0, stream>>>(x2b, Wb, nullptr, Kt, nullptr,
                                      4096, 4096, 4096, 1.0f, 16);
  // V = x2 @ Wv^T -> Vt
  cast_k<<<2048, 256, 0, stream>>>(Wv, Wb, 4194304);
  gemm256<0><<<512, 512, 0, stream>>>(x2b, Wb, nullptr, Vt, nullptr,
                                      4096, 4096, 4096, 1.0f, 16);

  // S = q^T k per head -> f32 logits into d_out attn region
  gemm_bt<1><<<dim3(2, 2, 512), 256, 0, stream>>>(Qt, Kt, outA, nullptr, 256, 256, 256);
  // softmax rows in-place; bf16 attn copy into x1b
  softmax_k<<<32768, 256, 0, stream>>>(outA, x1b);
  // out = attn @ v per head -> bf16 x-layout into x2b
  gemm_bt<2><<<dim3(2, 2, 512), 256, 0, stream>>>(x1b, Vt, nullptr, x2b, 256, 256, 256);

  // x = out @ Wp^T + bp -> d_out
  cast_k<<<2048, 256, 0, stream>>>(Wp, Wb, 4194304);
  gemm256<3><<<512, 512, 0, stream>>>(x2b, Wb, outX, nullptr, bp,
                                      4096, 4096, 4096, 1.0f, 16);
}